// Round 5
// baseline (566.974 us; speedup 1.0000x reference)
//
#include <hip/hip_runtime.h>
#include <math.h>

// SPMoEAdaptor: fused 2-layer soft-MoE + residual, N=524288, D=64, E=4.
// out = x + MoE_b(MoE_a(x));  MoE(v) = sum_e softmax(v@Wg)[e] * (v@W_e - b_e@W_e)
// Dtypes (confirmed R4 counters: WRITE_SIZE 132MB = N*64*4): fp32 in, fp32 out.
//
// R5: occupancy attack. 1024-thr blocks (16 waves, 1 block/CU, LDS 141KB),
// 512 blocks x 1 tile(64 tok)/wave. Softmax via shfl_xor (no LDS, no max-sub;
// logits bounded ~1). Gates packed bf16x2, shfl-broadcast in e-loop.
// fp32 epilogue staged through LDS -> float4 residual + float4 stores.
// b_exp==0 in harness: block-uniform hasC skips the ce subtraction (slow path kept).
//
// MFMA 16x16x32_bf16 layouts (m89/m91): A: row=lane&15, k=(lane>>4)*8+j ;
// B: col=lane&15, same k ; C: col=lane&15, row=(lane>>4)*4+reg.

typedef __attribute__((ext_vector_type(8))) short short8;
typedef __attribute__((ext_vector_type(4))) float floatx4;

__device__ __forceinline__ float bf2f(unsigned short s) {
    unsigned int u = ((unsigned int)s) << 16;
    return __builtin_bit_cast(float, u);
}
__device__ __forceinline__ unsigned short f2bf(float f) {
    unsigned int u = __builtin_bit_cast(unsigned int, f);
    u += 0x7fffu + ((u >> 16) & 1u);   // RNE
    return (unsigned short)(u >> 16);
}
__device__ __forceinline__ float hi2f(unsigned int p) {   // high bf16 of dword
    return __builtin_bit_cast(float, p & 0xffff0000u);
}
__device__ __forceinline__ float lo2f(unsigned int p) {   // low bf16 of dword
    return __builtin_bit_cast(float, p << 16);
}

struct CTrue  { static constexpr bool value = true;  };
struct CFalse { static constexpr bool value = false; };

#define NBLK 512

__global__ __launch_bounds__(1024)
void moe2_fused(const float* __restrict__ x,
                const float* __restrict__ wg_a,
                const float* __restrict__ we_a,
                const float* __restrict__ be_a,
                const float* __restrict__ wg_b,
                const float* __restrict__ we_b,
                const float* __restrict__ be_b,
                float* __restrict__ out)
{
    __shared__ alignas(16) short sB[2][17408];   // weights, fragment-major bf16 (69632 B)
    __shared__ float sC[2][4][64];               // c_e[f] = b_e @ W_e (2048 B)
    __shared__ int sHasC;
    __shared__ alignas(16) float sStg[16][1088]; // per-wave 16x68 fp32 stage (69632 B)

    const int tid = threadIdx.x;

    if (tid == 0) sHasC = 0;
    __syncthreads();

    // ---- stage weights into LDS (fp32 -> bf16), fragment-major ----
    for (int idx = tid; idx < 2 * 17 * 2 * 64; idx += 1024) {
        const int L   = idx / 2176;
        const int rem = idx - L * 2176;        // (t*2+kap)*64 + lane
        const int t   = rem >> 7;
        const int kap = (rem >> 6) & 1;
        const int l2  = rem & 63;
        const int kb  = kap * 32 + (l2 >> 4) * 8;
        const int cc  = l2 & 15;
        const float* we = L ? we_b : we_a;
        const float* wg = L ? wg_b : wg_a;
        short* dst = &sB[L][rem * 8];
        if (t < 16) {
            const int e = t >> 2;
            const int f = (t & 3) * 16 + cc;
            #pragma unroll
            for (int j = 0; j < 8; ++j)
                dst[j] = (short)f2bf(we[(e * 64 + kb + j) * 64 + f]);  // w_exp[e][k][f]
        } else {  // gate tile: cols 0..3 = Wg, rest zero
            #pragma unroll
            for (int j = 0; j < 8; ++j)
                dst[j] = (cc < 4) ? (short)f2bf(wg[(kb + j) * 4 + cc]) : (short)0;
        }
    }
    // ---- c_e[f] = b_e @ W_e (fp32); flag if any nonzero ----
    for (int idx = tid; idx < 512; idx += 1024) {
        const int L = idx >> 8;
        const int e = (idx >> 6) & 3;
        const int f = idx & 63;
        const float* we = L ? we_b : we_a;
        const float* be = L ? be_b : be_a;
        float s = 0.f;
        for (int d = 0; d < 64; ++d)
            s += be[e * 64 + d] * we[(e * 64 + d) * 64 + f];
        sC[L][e][f] = s;
        if (s != 0.f) atomicExch(&sHasC, 1);
    }
    __syncthreads();
    const bool hasC = (sHasC != 0);

    const int l  = tid & 63;
    const int wv = tid >> 6;       // 0..15
    const int c  = l & 15;         // C-layout col AND A-layout row for this lane
    const int q  = l >> 4;
    float* stgF = &sStg[wv][0];
    short* stgS = (short*)stgF;

    const int tile = blockIdx.x * 16 + wv;
    const size_t tok0 = (size_t)tile * 64;

    // one MoE layer: aF (A-frags) -> acc[sub][tt][reg] (C-layout fp32)
    auto runLayer = [&](const short8 (&aF)[4][2], const int L, float (&acc)[4][4][4]) {
        const short* BL = &sB[L][0];
        // gate logits + softmax (shfl_xor over the 4 expert lanes; no max-sub:
        // |logit| <~ 1 with w~0.02, overflow impossible). Gates packed bf16x2.
        unsigned int gp[4][2];
        {
            const short8 B0 = *(const short8*)&BL[(32 + 0) * 512 + l * 8];
            const short8 B1 = *(const short8*)&BL[(32 + 1) * 512 + l * 8];
            #pragma unroll
            for (int s = 0; s < 4; ++s) {
                floatx4 z = {0.f, 0.f, 0.f, 0.f};
                z = __builtin_amdgcn_mfma_f32_16x16x32_bf16(aF[s][0], B0, z, 0, 0, 0);
                z = __builtin_amdgcn_mfma_f32_16x16x32_bf16(aF[s][1], B1, z, 0, 0, 0);
                float g[4];
                #pragma unroll
                for (int r = 0; r < 4; ++r) {
                    const float ev = __expf(z[r]);
                    const float s2 = ev + __shfl_xor(ev, 1, 64);
                    const float sm = s2 + __shfl_xor(s2, 2, 64);
                    g[r] = ev * __builtin_amdgcn_rcpf(sm);
                }
                gp[s][0] = (unsigned int)f2bf(g[0]) | ((unsigned int)f2bf(g[1]) << 16);
                gp[s][1] = (unsigned int)f2bf(g[2]) | ((unsigned int)f2bf(g[3]) << 16);
            }
        }

        #pragma unroll
        for (int s = 0; s < 4; ++s)
            #pragma unroll
            for (int tt = 0; tt < 4; ++tt)
                #pragma unroll
                for (int r = 0; r < 4; ++r)
                    acc[s][tt][r] = 0.f;

        auto eloop = [&](auto HC) {
            constexpr bool hc = decltype(HC)::value;
            #pragma unroll
            for (int e = 0; e < 4; ++e) {
                // broadcast expert-e gates from lane (l&48)+e (2 shfls per s)
                unsigned int gs[4][2];
                #pragma unroll
                for (int s = 0; s < 4; ++s) {
                    gs[s][0] = __shfl(gp[s][0], (l & 48) + e, 64);
                    gs[s][1] = __shfl(gp[s][1], (l & 48) + e, 64);
                }
                #pragma unroll
                for (int tt = 0; tt < 4; ++tt) {
                    const int t = e * 4 + tt;
                    const short8 B0 = *(const short8*)&BL[(t * 2 + 0) * 512 + l * 8];
                    const short8 B1 = *(const short8*)&BL[(t * 2 + 1) * 512 + l * 8];
                    float ce = 0.f;
                    if constexpr (hc) ce = sC[L][e][tt * 16 + c];
                    #pragma unroll
                    for (int s = 0; s < 4; ++s) {
                        floatx4 z = {0.f, 0.f, 0.f, 0.f};
                        z = __builtin_amdgcn_mfma_f32_16x16x32_bf16(aF[s][0], B0, z, 0, 0, 0);
                        z = __builtin_amdgcn_mfma_f32_16x16x32_bf16(aF[s][1], B1, z, 0, 0, 0);
                        const float g0 = lo2f(gs[s][0]), g1 = hi2f(gs[s][0]);
                        const float g2 = lo2f(gs[s][1]), g3 = hi2f(gs[s][1]);
                        if constexpr (hc) {
                            acc[s][tt][0] += g0 * (z[0] - ce);
                            acc[s][tt][1] += g1 * (z[1] - ce);
                            acc[s][tt][2] += g2 * (z[2] - ce);
                            acc[s][tt][3] += g3 * (z[3] - ce);
                        } else {
                            acc[s][tt][0] += g0 * z[0];
                            acc[s][tt][1] += g1 * z[1];
                            acc[s][tt][2] += g2 * z[2];
                            acc[s][tt][3] += g3 * z[3];
                        }
                    }
                }
            }
        };
        if (hasC) eloop(CTrue{}); else eloop(CFalse{});
    };

    // ---- x (fp32) -> bf16 A-frags ----
    short8 xF[4][2];
    #pragma unroll
    for (int s = 0; s < 4; ++s)
        #pragma unroll
        for (int k = 0; k < 2; ++k) {
            const float* xr = x + (tok0 + s * 16 + c) * 64 + k * 32 + q * 8;
            const floatx4 v0 = *(const floatx4*)xr;
            const floatx4 v1 = *(const floatx4*)(xr + 4);
            short8 f;
            #pragma unroll
            for (int j = 0; j < 4; ++j) {
                f[j]     = (short)f2bf(v0[j]);
                f[4 + j] = (short)f2bf(v1[j]);
            }
            xF[s][k] = f;
        }

    float acc[4][4][4];
    runLayer(xF, 0, acc);

    // ---- h: C-layout fp32 -> bf16 LDS (wave-private, stride 72) -> A-frags ----
    short8 hF[4][2];
    #pragma unroll
    for (int s = 0; s < 4; ++s) {
        #pragma unroll
        for (int tt = 0; tt < 4; ++tt)
            #pragma unroll
            for (int r = 0; r < 4; ++r)
                stgS[(4 * q + r) * 72 + tt * 16 + c] = (short)f2bf(acc[s][tt][r]);
        hF[s][0] = *(const short8*)&stgS[c * 72 + q * 8];
        hF[s][1] = *(const short8*)&stgS[c * 72 + 32 + q * 8];
    }

    runLayer(hF, 1, acc);

    // ---- epilogue: acc -> LDS (fp32, stride 68) -> +x residual -> float4 stores ----
    const int rE = l >> 2;        // 0..15: row within subtile
    const int aE = l & 3;         // 0..3 : 16B chunk within 64B row-quarter
    #pragma unroll
    for (int s = 0; s < 4; ++s) {
        #pragma unroll
        for (int tt = 0; tt < 4; ++tt)
            #pragma unroll
            for (int r = 0; r < 4; ++r)
                stgF[(4 * q + r) * 68 + tt * 16 + c] = acc[s][tt][r];
        const float* xrow = x   + (tok0 + s * 16 + rE) * 64;
        float*       orow = out + (tok0 + s * 16 + rE) * 64;
        #pragma unroll
        for (int j = 0; j < 4; ++j) {
            const int col = aE * 4 + j * 16;
            const floatx4 v  = *(const floatx4*)&stgF[rE * 68 + col];
            const floatx4 xr = *(const floatx4*)&xrow[col];
            *(floatx4*)&orow[col] = v + xr;
        }
    }
}

extern "C" void kernel_launch(void* const* d_in, const int* in_sizes, int n_in,
                              void* d_out, int out_size, void* d_ws, size_t ws_size,
                              hipStream_t stream) {
    hipLaunchKernelGGL(moe2_fused, dim3(NBLK), dim3(1024), 0, stream,
                       (const float*)d_in[0], (const float*)d_in[1],
                       (const float*)d_in[2], (const float*)d_in[3],
                       (const float*)d_in[4], (const float*)d_in[5],
                       (const float*)d_in[6], (float*)d_out);
}